// Round 10
// baseline (137.187 us; speedup 1.0000x reference)
//
#include <hip/hip_runtime.h>

// HarmonicConvolutionFilter on MI355X (round 10 = round 8 resubmit x2; GPU timeouts).
// x: [B=4, S=1024, F=512, C=4] f32;  W: [5, K=4, C=4, O=4] f32;  out: [B,S,F,4] f32
//
// DIAGNOSTIC round. Rounds 5-7: three traffic/latency fixes all null
// (dur_us 95.9/94.9/93.5). Kernel time has been INFERRED (dur_us - 63.7us
// restore) since round 2 -- never measured, because ~43us poison-fills hide
// it in top-5. This round repeats the round-6 body 4x inside the kernel
// (barriers + memory clobber prevent cross-rep elision) so the dispatch
// surfaces in top-5 with true per-dispatch counters. dispatch/4 ~= true T:
//   Model A (overhead fixed 63.7): T ~= 30us -> 20us headroom remains.
//   Model B (overhead ~80us):      T ~= 15us -> near HBM floor (10.6us).
// Also reads: VALUBusy (stall regime), SQ_LDS_BANK_CONFLICT (swz validity),
// FETCH_SIZE (true read traffic), OccupancyPercent.

#define TS    2      // time strip per thread
#define NTAP  5
#define FB    512
#define SB    1024
#define BB    4
#define NROW  (TS + 4)          // 6 rows staged (TS + 2*halo)
#define ROWP  544               // 512 + 32 pad slots (one per 16), float4 units
#define NREP  4                 // diagnostic repetition factor

typedef float vfloat4 __attribute__((ext_vector_type(4)));

__device__ __forceinline__ void nt_store4(float4 v, float4* p) {
    vfloat4 raw = { v.x, v.y, v.z, v.w };
    __builtin_nontemporal_store(raw, (vfloat4*)p);
}

__device__ __forceinline__ int swz(int f) { return f + (f >> 4); }

// accumulate harmonic with weights Wk = W + (m-1)*16, source column g = f*m
__device__ __forceinline__ void accum_harm(const float4* lx, int g,
                                           const float* __restrict__ Wk,
                                           float4 acc[TS]) {
    float4 xw[NROW];
#pragma unroll
    for (int r = 0; r < NROW; ++r) xw[r] = lx[r * ROWP + swz(g)];
#pragma unroll
    for (int t = 0; t < NTAP; ++t) {
        const float* wp = Wk + t * 64;   // uniform address -> scalar loads
        float w[16];
#pragma unroll
        for (int i = 0; i < 16; ++i) w[i] = wp[i];
#pragma unroll
        for (int j = 0; j < TS; ++j) {
            const float4 xv = xw[j + t];
            acc[j].x += xv.x*w[0] + xv.y*w[4] + xv.z*w[8]  + xv.w*w[12];
            acc[j].y += xv.x*w[1] + xv.y*w[5] + xv.z*w[9]  + xv.w*w[13];
            acc[j].z += xv.x*w[2] + xv.y*w[6] + xv.z*w[10] + xv.w*w[14];
            acc[j].w += xv.x*w[3] + xv.y*w[7] + xv.z*w[11] + xv.w*w[15];
        }
    }
}

__global__ __launch_bounds__(256, 3)
void harmonic_conv_kernel(const float* __restrict__ x,
                          const float* __restrict__ W,
                          float* __restrict__ out) {
    __shared__ float4 lx[NROW * ROWP];   // 6*544*16B = 51KB

    // grid: BB * (SB/TS) = 2048 blocks of 256 threads
    const int bid  = blockIdx.x;
    const int work = ((bid & 7) << 8) | (bid >> 3);   // XCD-contiguous chunks
    const int b    = work >> 9;                       // 0..3
    const int s0   = (work & 511) * TS;               // 0..1022
    const int tid  = threadIdx.x;

    const float4* xb = (const float4*)x + (size_t)b * SB * FB;
    float4*       ob = (float4*)out + (size_t)b * SB * FB;

#pragma unroll 1
    for (int rep = 0; rep < NREP; ++rep) {
        // ---- stage 6 rows x 512 f (coalesced); pad rows -> 0 ----
#pragma unroll
        for (int i = 0; i < NROW * FB / 256; ++i) {   // 12 iters
            const int n  = i * 256 + tid;
            const int r  = n >> 9;                    // uniform per iter
            const int f  = n & (FB - 1);
            const int sp = s0 + r - 2;                // uniform predicate
            float4 v = make_float4(0.f, 0.f, 0.f, 0.f);
            if (sp >= 0 && sp < SB) v = xb[(size_t)sp * FB + f];
            lx[r * ROWP + swz(f)] = v;
        }
        __syncthreads();

        float4 acc[TS];

        // ---- high half: f = tid + 256, only m=1 valid ----
#pragma unroll
        for (int j = 0; j < TS; ++j) acc[j] = make_float4(0.f, 0.f, 0.f, 0.f);
        accum_harm(lx, tid + 256, W, acc);
#pragma unroll
        for (int j = 0; j < TS; ++j)
            nt_store4(acc[j], &ob[(size_t)(s0 + j) * FB + (tid + 256)]);

        // ---- low half: f = tid, harmonics m=1..4 ----
#pragma unroll
        for (int j = 0; j < TS; ++j) acc[j] = make_float4(0.f, 0.f, 0.f, 0.f);
        accum_harm(lx, tid,     W,      acc);             // m=1
        accum_harm(lx, tid * 2, W + 16, acc);             // m=2
        if (tid * 3 < FB) accum_harm(lx, tid * 3, W + 32, acc);   // m=3
        if (tid * 4 < FB) accum_harm(lx, tid * 4, W + 48, acc);   // m=4
#pragma unroll
        for (int j = 0; j < TS; ++j)
            nt_store4(acc[j], &ob[(size_t)(s0 + j) * FB + tid]);

        // reps must not race (next stage overwrites lx) and must not be
        // CSE'd/elided (memory clobber = opaque observer between reps)
        __syncthreads();
        asm volatile("" ::: "memory");
    }
}

extern "C" void kernel_launch(void* const* d_in, const int* in_sizes, int n_in,
                              void* d_out, int out_size, void* d_ws, size_t ws_size,
                              hipStream_t stream) {
    const float* x = (const float*)d_in[0];
    const float* W = (const float*)d_in[1];
    float* out = (float*)d_out;
    const int nblocks = BB * (SB / TS);   // 2048
    harmonic_conv_kernel<<<nblocks, 256, 0, stream>>>(x, W, out);
}